// Round 7
// baseline (783.856 us; speedup 1.0000x reference)
//
#include <hip/hip_runtime.h>
#include <hip/hip_bf16.h>
#include <stdint.h>

typedef __attribute__((ext_vector_type(8))) __bf16 bf16x8;
typedef __attribute__((ext_vector_type(4))) float floatx4;

#define C 128
#define TROWS 16   // rows per ticket = one wave-tile

__device__ __forceinline__ __bf16 f2b(float f) {
  return __builtin_bit_cast(__bf16, __float2bfloat16(f));
}

// histogram of row indices + W fp32 -> bf16 conversion
__global__ void prep_kernel(const int* __restrict__ rowidx, const float* __restrict__ W,
                            int* __restrict__ deg, __bf16* __restrict__ Wb, int n) {
  int i = blockIdx.x * blockDim.x + threadIdx.x;
  if (i < C * C) Wb[i] = f2b(W[i]);
  if (i < n) atomicAdd(deg + rowidx[i], 1);
}

// result[j] = (x[j] + x[col[j]]) @ W.T + 2*b + deg[j]
// R7: persistent blocks + GLOBAL ATOMIC TICKET (16-row tickets, one per wave).
//  - Issue order is globally sequential (like R3's hardware dispatch, which
//    kept FETCH/WRITE at the 512MB floor); frontier = resident waves x 16
//    rows ~= 82K rows, between R3's 65K (good) and R4's 131K (ok).
//  - W staged ONCE per block (L2 W-traffic /8); ZERO barriers in the loop
//    (R1-verified: barrier-free persistent loop ran at 3.44 TB/s).
//  - Next ticket + colidx + deg prefetched during current tile's MFMA.
__launch_bounds__(256, 5)
__global__ void gconv_kernel(const float* __restrict__ x,
                             const int* __restrict__ colidx,
                             const __bf16* __restrict__ Wb,
                             const float* __restrict__ bias,
                             const int* __restrict__ deg,
                             int* __restrict__ ticket,
                             float* __restrict__ out, int n) {
  __shared__ bf16x8 sW[2048];   // 32768 B: row r = slots [r*16, r*16+16), slot ^= (r&15)

  const int t = threadIdx.x;
  const int lane = t & 63;
  const int l15 = lane & 15, quad = lane >> 4;

  // ---- stage W once per block ----
  {
    int r = t >> 1, h = t & 1, rx = r & 15;
    const bf16x8* src = (const bf16x8*)(Wb + r * C) + h * 8;
    bf16x8 wreg[8];
#pragma unroll
    for (int i = 0; i < 8; i++) wreg[i] = src[i];
#pragma unroll
    for (int i = 0; i < 8; i++) sW[r * 16 + ((h * 8 + i) ^ rx)] = wreg[i];
  }

  // per-lane bias (col = tt*16 + l15)
  float b2[8];
#pragma unroll
  for (int tt = 0; tt < 8; tt++) b2[tt] = 2.0f * bias[tt * 16 + l15];

  const int ntk = (n + TROWS - 1) / TROWS;   // 31250 for n=500000 (exact)

  __syncthreads();
  // steady state below is barrier-free: sW is read-only from here on

  // B frag (kc,tt): row nrow = tt*16+l15, 16B-slot (quad+kc*4) ^ (nrow&15)
  const bf16x8* wr0 = sW + l15 * 16 + ((quad + 0)  ^ l15);
  const bf16x8* wr1 = sW + l15 * 16 + ((quad + 4)  ^ l15);
  const bf16x8* wr2 = sW + l15 * 16 + ((quad + 8)  ^ l15);
  const bf16x8* wr3 = sW + l15 * 16 + ((quad + 12) ^ l15);

  // ---- first ticket + its index/deg loads ----
  int tk;
  if (lane == 0) tk = atomicAdd(ticket, 1);
  tk = __shfl(tk, 0);
  {
    int sb = (tk < ntk ? tk : 0) * TROWS;
    int ga = sb + l15;          int gal = ga < n ? ga : n - 1;
    int gr = sb + quad * 4;     int grl = (gr + 3 < n) ? gr : ((n - 4) & ~3);
    int cg = colidx[gal];
    int4 d4 = *(const int4*)(deg + grl);

    while (tk < ntk) {
      const int base = tk * TROWS;
      int row0 = base + l15; if (row0 >= n) row0 = n - 1;

      // ---- A-side burst: 16 float4 loads per lane (dense row + gathered row) ----
      const floatx4* pa = (const floatx4*)(x + (size_t)row0 * C) + quad * 2;
      const floatx4* pc = (const floatx4*)(x + (size_t)cg   * C) + quad * 2;
      floatx4 va[8], vc[8];
#pragma unroll
      for (int kc = 0; kc < 4; kc++) {
        va[2 * kc]     = pa[kc * 8];
        va[2 * kc + 1] = pa[kc * 8 + 1];
        vc[2 * kc]     = pc[kc * 8];
        vc[2 * kc + 1] = pc[kc * 8 + 1];
      }

      // ---- grab + prefetch NEXT ticket's colidx/deg (hides atomic+idx latency) ----
      int nt;
      if (lane == 0) nt = atomicAdd(ticket, 1);
      nt = __shfl(nt, 0);
      int nsb = (nt < ntk ? nt : 0) * TROWS;
      int nga = nsb + l15;      int ngal = nga < n ? nga : n - 1;
      int ngr = nsb + quad * 4; int ngrl = (ngr + 3 < n) ? ngr : ((n - 4) & ~3);
      int ncg = colidx[ngal];
      int4 nd4 = *(const int4*)(deg + ngrl);

      // ---- convert A fragments ----
      bf16x8 av[4];
#pragma unroll
      for (int kc = 0; kc < 4; kc++) {
        floatx4 a0 = va[2 * kc], a1 = va[2 * kc + 1];
        floatx4 c0 = vc[2 * kc], c1 = vc[2 * kc + 1];
        av[kc][0] = f2b(a0[0] + c0[0]); av[kc][1] = f2b(a0[1] + c0[1]);
        av[kc][2] = f2b(a0[2] + c0[2]); av[kc][3] = f2b(a0[3] + c0[3]);
        av[kc][4] = f2b(a1[0] + c1[0]); av[kc][5] = f2b(a1[1] + c1[1]);
        av[kc][6] = f2b(a1[2] + c1[2]); av[kc][7] = f2b(a1[3] + c1[3]);
      }

      // ---- MFMA ----
      floatx4 acc[8];
#pragma unroll
      for (int i = 0; i < 8; i++) acc[i] = (floatx4){0.f, 0.f, 0.f, 0.f};
#pragma unroll
      for (int tt = 0; tt < 8; tt++) {
        acc[tt] = __builtin_amdgcn_mfma_f32_16x16x32_bf16(av[0], wr0[tt * 256], acc[tt], 0, 0, 0);
        acc[tt] = __builtin_amdgcn_mfma_f32_16x16x32_bf16(av[1], wr1[tt * 256], acc[tt], 0, 0, 0);
        acc[tt] = __builtin_amdgcn_mfma_f32_16x16x32_bf16(av[2], wr2[tt * 256], acc[tt], 0, 0, 0);
        acc[tt] = __builtin_amdgcn_mfma_f32_16x16x32_bf16(av[3], wr3[tt * 256], acc[tt], 0, 0, 0);
      }

      // ---- epilogue: C/D layout col=l15, row=quad*4+reg (HW-verified) ----
      float dvf[4];
      dvf[0] = (float)d4.x; dvf[1] = (float)d4.y;
      dvf[2] = (float)d4.z; dvf[3] = (float)d4.w;
#pragma unroll
      for (int r = 0; r < 4; r++) {
        int g = gr + r;
        if (g < n) {
          float* orow = out + (size_t)g * C + l15;
          float dv = dvf[r];
#pragma unroll
          for (int tt = 0; tt < 8; tt++) orow[tt * 16] = acc[tt][r] + b2[tt] + dv;
        }
      }

      // rotate pipeline state
      tk = nt; cg = ncg; d4 = nd4; gr = ngr;
    }
  }
}

extern "C" void kernel_launch(void* const* d_in, const int* in_sizes, int n_in,
                              void* d_out, int out_size, void* d_ws, size_t ws_size,
                              hipStream_t stream) {
  const float* x    = (const float*)d_in[0];
  const int*   edge = (const int*)d_in[1];   // [2, n] flat: first n = row, next n = col
  const float* W    = (const float*)d_in[2];
  const float* bias = (const float*)d_in[3];
  float* out = (float*)d_out;

  const int n = in_sizes[0] / C;             // 500000

  int* deg = (int*)d_ws;
  size_t wb_off = ((size_t)n * sizeof(int) + 255) & ~(size_t)255;
  __bf16* Wb = (__bf16*)((char*)d_ws + wb_off);
  size_t tk_off = wb_off + (((size_t)C * C * sizeof(__bf16) + 255) & ~(size_t)255);
  int* ticket = (int*)((char*)d_ws + tk_off);

  hipMemsetAsync(deg, 0, (size_t)n * sizeof(int), stream);
  hipMemsetAsync(ticket, 0, sizeof(int), stream);

  int nb = (n + 255) / 256;
  prep_kernel<<<nb, 256, 0, stream>>>(edge, W, deg, Wb, n);

  // persistent: 5 blocks/CU x 256 CUs (LDS 32KB -> 5/CU; launch_bounds(256,5) caps VGPR at 102)
  gconv_kernel<<<1280, 256, 0, stream>>>(x, edge + n, Wb, bias, deg, ticket, out, n);
}

// Round 8
// 520.389 us; speedup vs baseline: 1.5063x; 1.5063x over previous
//
#include <hip/hip_runtime.h>
#include <hip/hip_bf16.h>
#include <stdint.h>

typedef __attribute__((ext_vector_type(8))) __bf16 bf16x8;
typedef __attribute__((ext_vector_type(4))) float floatx4;

#define C 128
#define BROWS 128   // rows per block: 8 waves x 16-row wave-tiles

__device__ __forceinline__ __bf16 f2b(float f) {
  return __builtin_bit_cast(__bf16, __float2bfloat16(f));
}

// histogram of row indices + W fp32 -> bf16 conversion
__global__ void prep_kernel(const int* __restrict__ rowidx, const float* __restrict__ W,
                            int* __restrict__ deg, __bf16* __restrict__ Wb, int n) {
  int i = blockIdx.x * blockDim.x + threadIdx.x;
  if (i < C * C) Wb[i] = f2b(W[i]);
  if (i < n) atomicAdd(deg + rowidx[i], 1);
}

// result[j] = (x[j] + x[col[j]]) @ W.T + 2*b + deg[j]
// ONE-SHOT blocks in hardware dispatch order -- the only regime that holds
// FETCH/WRITE at the 512MB floor (persistence falsified 3 ways: grid-stride
// 534MB / chunked 533MB / atomic-ticket 749MB).
// R8 = rerun R4's occupancy experiment CLEANLY: 512-thr blocks fixed dispatch
// starvation (occ 75.6%) but launch_bounds(512,8) capped VGPR at 64 -> spills
// (VGPR_Count=32, +65MB scratch traffic). Now launch_bounds(512,6): cap 84 >=
// R6's measured need of 52 -> no spills, 3 blocks/CU = 24 waves = 75%.
__launch_bounds__(512, 6)
__global__ void gconv_kernel(const float* __restrict__ x,
                             const int* __restrict__ colidx,
                             const __bf16* __restrict__ Wb,
                             const float* __restrict__ bias,
                             const int* __restrict__ deg,
                             float* __restrict__ out, int n) {
  __shared__ bf16x8 sW[2048];   // 32768 B: row r = slots [r*16, r*16+16), slot ^= (r&15)

  const int t = threadIdx.x;
  const int lane = t & 63, w = t >> 6;          // w in 0..7
  const int l15 = lane & 15, quad = lane >> 4;

  const int base = blockIdx.x * BROWS + w * 16;

  // index load first: its latency hides under W staging
  int ga  = base + l15;
  int gal = ga < n ? ga : n - 1;
  int cg  = colidx[gal];

  // ---- stage W: thread t covers row r=t>>2, quarter q=t&3 (4 x 16B slots) ----
  {
    int r = t >> 2, q = t & 3, rx = r & 15;
    const bf16x8* src = (const bf16x8*)(Wb + r * C) + q * 4;
    bf16x8 wreg[4];
#pragma unroll
    for (int i = 0; i < 4; i++) wreg[i] = src[i];
#pragma unroll
    for (int i = 0; i < 4; i++) sW[r * 16 + ((q * 4 + i) ^ rx)] = wreg[i];
  }

  // ---- A-side burst: 16 float4 loads per lane, straight from global ----
  // lane (l15, quad) owns row base+l15, k = quad*8 + kc*32 + j
  const floatx4* pa = (const floatx4*)(x + (size_t)gal * C) + quad * 2;
  const floatx4* pc = (const floatx4*)(x + (size_t)cg  * C) + quad * 2;
  floatx4 va[8], vc[8];
#pragma unroll
  for (int kc = 0; kc < 4; kc++) {
    va[2 * kc]     = pa[kc * 8];
    va[2 * kc + 1] = pa[kc * 8 + 1];
    vc[2 * kc]     = pc[kc * 8];
    vc[2 * kc + 1] = pc[kc * 8 + 1];
  }

  // deg for the 4 epilogue rows of this lane (row = base + quad*4 + r)
  int gr  = base + quad * 4;
  int grl = (gr + 3 < n) ? gr : ((n - 4) & ~3);
  int4 d4 = *(const int4*)(deg + grl);

  // per-lane bias (col = tt*16 + l15)
  float b2[8];
#pragma unroll
  for (int tt = 0; tt < 8; tt++) b2[tt] = 2.0f * bias[tt * 16 + l15];

  __syncthreads();

  // ---- convert A fragments ----
  bf16x8 av[4];
#pragma unroll
  for (int kc = 0; kc < 4; kc++) {
    floatx4 a0 = va[2 * kc], a1 = va[2 * kc + 1];
    floatx4 c0 = vc[2 * kc], c1 = vc[2 * kc + 1];
    av[kc][0] = f2b(a0[0] + c0[0]); av[kc][1] = f2b(a0[1] + c0[1]);
    av[kc][2] = f2b(a0[2] + c0[2]); av[kc][3] = f2b(a0[3] + c0[3]);
    av[kc][4] = f2b(a1[0] + c1[0]); av[kc][5] = f2b(a1[1] + c1[1]);
    av[kc][6] = f2b(a1[2] + c1[2]); av[kc][7] = f2b(a1[3] + c1[3]);
  }

  // B frag (kc,tt): row nrow = tt*16+l15, 16B-slot (quad+kc*4) ^ (nrow&15)
  const bf16x8* wr0 = sW + l15 * 16 + ((quad + 0)  ^ l15);
  const bf16x8* wr1 = sW + l15 * 16 + ((quad + 4)  ^ l15);
  const bf16x8* wr2 = sW + l15 * 16 + ((quad + 8)  ^ l15);
  const bf16x8* wr3 = sW + l15 * 16 + ((quad + 12) ^ l15);

  floatx4 acc[8];
#pragma unroll
  for (int i = 0; i < 8; i++) acc[i] = (floatx4){0.f, 0.f, 0.f, 0.f};

#pragma unroll
  for (int tt = 0; tt < 8; tt++) {
    acc[tt] = __builtin_amdgcn_mfma_f32_16x16x32_bf16(av[0], wr0[tt * 256], acc[tt], 0, 0, 0);
    acc[tt] = __builtin_amdgcn_mfma_f32_16x16x32_bf16(av[1], wr1[tt * 256], acc[tt], 0, 0, 0);
    acc[tt] = __builtin_amdgcn_mfma_f32_16x16x32_bf16(av[2], wr2[tt * 256], acc[tt], 0, 0, 0);
    acc[tt] = __builtin_amdgcn_mfma_f32_16x16x32_bf16(av[3], wr3[tt * 256], acc[tt], 0, 0, 0);
  }

  // ---- epilogue: C/D layout col=l15, row=quad*4+reg (HW-verified) ----
  float dvf[4];
  dvf[0] = (float)d4.x; dvf[1] = (float)d4.y;
  dvf[2] = (float)d4.z; dvf[3] = (float)d4.w;
#pragma unroll
  for (int r = 0; r < 4; r++) {
    int g = gr + r;
    if (g < n) {
      float* orow = out + (size_t)g * C + l15;
      float dv = dvf[r];
#pragma unroll
      for (int tt = 0; tt < 8; tt++) orow[tt * 16] = acc[tt][r] + b2[tt] + dv;
    }
  }
}

extern "C" void kernel_launch(void* const* d_in, const int* in_sizes, int n_in,
                              void* d_out, int out_size, void* d_ws, size_t ws_size,
                              hipStream_t stream) {
  const float* x    = (const float*)d_in[0];
  const int*   edge = (const int*)d_in[1];   // [2, n] flat: first n = row, next n = col
  const float* W    = (const float*)d_in[2];
  const float* bias = (const float*)d_in[3];
  float* out = (float*)d_out;

  const int n = in_sizes[0] / C;             // 500000

  int* deg = (int*)d_ws;
  size_t wb_off = ((size_t)n * sizeof(int) + 255) & ~(size_t)255;
  __bf16* Wb = (__bf16*)((char*)d_ws + wb_off);

  hipMemsetAsync(deg, 0, (size_t)n * sizeof(int), stream);

  int nb = (n + 255) / 256;
  prep_kernel<<<nb, 256, 0, stream>>>(edge, W, deg, Wb, n);

  int mb = (n + BROWS - 1) / BROWS;          // 3907 blocks, one 128-row slab each
  gconv_kernel<<<mb, 512, 0, stream>>>(x, edge + n, Wb, bias, deg, out, n);
}

// Round 9
// 494.163 us; speedup vs baseline: 1.5862x; 1.0531x over previous
//
#include <hip/hip_runtime.h>
#include <hip/hip_bf16.h>
#include <stdint.h>

typedef __attribute__((ext_vector_type(8))) __bf16 bf16x8;
typedef __attribute__((ext_vector_type(4))) float floatx4;

#define C 128
#define BROWS 64

__device__ __forceinline__ __bf16 f2b(float f) {
  return __builtin_bit_cast(__bf16, __float2bfloat16(f));
}

// async 16B/lane global->LDS DMA: dest = uniform base + lane*16, src per-lane
__device__ __forceinline__ void gl2lds16(const void* g, void* l) {
  __builtin_amdgcn_global_load_lds(
      (const __attribute__((address_space(1))) void*)g,
      (__attribute__((address_space(3))) void*)l, 16, 0, 0);
}

// histogram of row indices + W fp32 -> bf16 conversion
__global__ void prep_kernel(const int* __restrict__ rowidx, const float* __restrict__ W,
                            int* __restrict__ deg, __bf16* __restrict__ Wb, int n) {
  int i = blockIdx.x * blockDim.x + threadIdx.x;
  if (i < C * C) Wb[i] = f2b(W[i]);
  if (i < n) atomicAdd(deg + rowidx[i], 1);
}

// result[j] = (x[j] + x[col[j]]) @ W.T + 2*b + deg[j]
// ONE-SHOT blocks, hardware dispatch order (only regime holding the 512MB
// traffic floor -- persistence falsified 3 ways R1/R2/R7).
// R9: ALL staging via global_load_lds DMA (W 32KB + dense 32KB + gather 32KB).
// Register-based bursts failed 4x (compiler sinks loads, VGPR 32..52); DMA
// depth is register-free: ~24 x 1KB in flight per wave during staging.
// LDS 96KB -> 1 block/CU: occupancy ~12% is EXPECTED; the bet is that DMA
// depth, not wave count, delivers the in-flight bytes (Little's law needs
// ~9KB/CU for 6.3TB/s; the burst holds ~64KB).
// Swizzle: LDS dest linear (HW requirement); 16B-chunk XOR applied on the
// per-lane SOURCE address; reads use the same XOR (involution, rule #21).
__launch_bounds__(256, 1)
__global__ void gconv_kernel(const float* __restrict__ x,
                             const int* __restrict__ colidx,
                             const __bf16* __restrict__ Wb,
                             const float* __restrict__ bias,
                             const int* __restrict__ deg,
                             float* __restrict__ out, int n) {
  __shared__ bf16x8 sW[2048];          // 32 KB: row r = slots [r*16,r*16+16), chunk c at slot c^(r&15)
  __shared__ float sD[BROWS * 128];    // 32 KB dense rows: chunk c of row r at slot c^(r&7)
  __shared__ float sG[BROWS * 128];    // 32 KB gather rows: same swizzle

  const int t = threadIdx.x;
  const int lane = t & 63, w = t >> 6;
  const int l15 = lane & 15, quad = lane >> 4;
  const int l31 = lane & 31, half = lane >> 5;
  const int base = blockIdx.x * BROWS;

  // ---- colidx for this wave's 16 rows (lane L holds row L&15) ----
  int gidx = base + w * 16 + l15;
  int cv = colidx[gidx < n ? gidx : n - 1];

  // ---- W via DMA: wave w stages W rows [w*32, w*32+32); 8 x 1KB ----
  // per inst: 4 W-rows (256B, 16 slots); lane L -> row +L>>4, slot L&15
#pragma unroll
  for (int i = 0; i < 8; i++) {
    int r = w * 32 + i * 4 + (lane >> 4);
    const __bf16* src = Wb + r * C + (((lane & 15) ^ (r & 15)) << 3);
    gl2lds16(src, &sW[(w * 32 + i * 4) * 16]);
  }

  // ---- dense x rows via DMA: wave w stages rows [w*16, w*16+16); 8 x 1KB ----
  // per inst: 2 rows (512B, 32 chunks); lane L -> row +half, slot l31
#pragma unroll
  for (int i = 0; i < 8; i++) {
    int rl = w * 16 + i * 2 + half;
    int gi = base + rl; if (gi >= n) gi = n - 1;
    const float* src = x + (size_t)gi * C + ((l31 ^ (rl & 7)) << 2);
    gl2lds16(src, &sD[(w * 16 + i * 2) * 128]);
  }

  // ---- gather rows via DMA (per-lane random source addresses) ----
#pragma unroll
  for (int i = 0; i < 8; i++) {
    int rl = w * 16 + i * 2 + half;
    int cg = __shfl(cv, i * 2 + half);
    const float* src = x + (size_t)cg * C + ((l31 ^ (rl & 7)) << 2);
    gl2lds16(src, &sG[(w * 16 + i * 2) * 128]);
  }

  // deg for the 4 epilogue rows of this lane (row = base + quad*4 + r)
  int gr  = base + w * 16 + quad * 4;
  int grl = (gr + 3 < n) ? gr : ((n - 4) & ~3);
  int4 d4 = *(const int4*)(deg + grl);

  // per-lane bias (col = tt*16 + l15)
  float b2[8];
#pragma unroll
  for (int tt = 0; tt < 8; tt++) b2[tt] = 2.0f * bias[tt * 16 + l15];

  __syncthreads();   // compiler emits vmcnt(0): all DMA landed, sW visible

  // ---- build A fragments from LDS: A[m=l15][k=quad*8+kc*32+j] ----
  const float* dR = sD + (w * 16 + l15) * 128;
  const float* gR = sG + (w * 16 + l15) * 128;
  const int s7 = l15 & 7;

  bf16x8 av[4];
#pragma unroll
  for (int kc = 0; kc < 4; kc++) {
    int c0 = 2 * quad + 8 * kc;   // even chunk index
    floatx4 d0 = *(const floatx4*)(dR + (((c0)     ^ s7) << 2));
    floatx4 d1 = *(const floatx4*)(dR + (((c0 + 1) ^ s7) << 2));
    floatx4 g0 = *(const floatx4*)(gR + (((c0)     ^ s7) << 2));
    floatx4 g1 = *(const floatx4*)(gR + (((c0 + 1) ^ s7) << 2));
    av[kc][0] = f2b(d0[0] + g0[0]); av[kc][1] = f2b(d0[1] + g0[1]);
    av[kc][2] = f2b(d0[2] + g0[2]); av[kc][3] = f2b(d0[3] + g0[3]);
    av[kc][4] = f2b(d1[0] + g1[0]); av[kc][5] = f2b(d1[1] + g1[1]);
    av[kc][6] = f2b(d1[2] + g1[2]); av[kc][7] = f2b(d1[3] + g1[3]);
  }

  // B frag (kc,tt): row nrow = tt*16+l15, chunk quad+kc*4 at slot (quad+kc*4)^l15
  const bf16x8* wr0 = sW + l15 * 16 + ((quad + 0)  ^ l15);
  const bf16x8* wr1 = sW + l15 * 16 + ((quad + 4)  ^ l15);
  const bf16x8* wr2 = sW + l15 * 16 + ((quad + 8)  ^ l15);
  const bf16x8* wr3 = sW + l15 * 16 + ((quad + 12) ^ l15);

  floatx4 acc[8];
#pragma unroll
  for (int i = 0; i < 8; i++) acc[i] = (floatx4){0.f, 0.f, 0.f, 0.f};

#pragma unroll
  for (int tt = 0; tt < 8; tt++) {
    acc[tt] = __builtin_amdgcn_mfma_f32_16x16x32_bf16(av[0], wr0[tt * 256], acc[tt], 0, 0, 0);
    acc[tt] = __builtin_amdgcn_mfma_f32_16x16x32_bf16(av[1], wr1[tt * 256], acc[tt], 0, 0, 0);
    acc[tt] = __builtin_amdgcn_mfma_f32_16x16x32_bf16(av[2], wr2[tt * 256], acc[tt], 0, 0, 0);
    acc[tt] = __builtin_amdgcn_mfma_f32_16x16x32_bf16(av[3], wr3[tt * 256], acc[tt], 0, 0, 0);
  }

  // ---- epilogue: C/D layout col=l15, row=quad*4+reg (HW-verified) ----
  float dvf[4];
  dvf[0] = (float)d4.x; dvf[1] = (float)d4.y;
  dvf[2] = (float)d4.z; dvf[3] = (float)d4.w;
#pragma unroll
  for (int r = 0; r < 4; r++) {
    int g = gr + r;
    if (g < n) {
      float* orow = out + (size_t)g * C + l15;
      float dv = dvf[r];
#pragma unroll
      for (int tt = 0; tt < 8; tt++) orow[tt * 16] = acc[tt][r] + b2[tt] + dv;
    }
  }
}

extern "C" void kernel_launch(void* const* d_in, const int* in_sizes, int n_in,
                              void* d_out, int out_size, void* d_ws, size_t ws_size,
                              hipStream_t stream) {
  const float* x    = (const float*)d_in[0];
  const int*   edge = (const int*)d_in[1];   // [2, n] flat: first n = row, next n = col
  const float* W    = (const float*)d_in[2];
  const float* bias = (const float*)d_in[3];
  float* out = (float*)d_out;

  const int n = in_sizes[0] / C;             // 500000

  int* deg = (int*)d_ws;
  size_t wb_off = ((size_t)n * sizeof(int) + 255) & ~(size_t)255;
  __bf16* Wb = (__bf16*)((char*)d_ws + wb_off);

  hipMemsetAsync(deg, 0, (size_t)n * sizeof(int), stream);

  int nb = (n + 255) / 256;
  prep_kernel<<<nb, 256, 0, stream>>>(edge, W, deg, Wb, n);

  int mb = (n + BROWS - 1) / BROWS;          // 7813 blocks, one 64-row tile each
  gconv_kernel<<<mb, 256, 0, stream>>>(x, edge + n, Wb, bias, deg, out, n);
}

// Round 10
// 480.170 us; speedup vs baseline: 1.6325x; 1.0291x over previous
//
#include <hip/hip_runtime.h>
#include <hip/hip_bf16.h>
#include <stdint.h>

typedef __attribute__((ext_vector_type(8))) __bf16 bf16x8;
typedef __attribute__((ext_vector_type(4))) float floatx4;

#define C 128
#define BROWS 64

__device__ __forceinline__ __bf16 f2b(float f) {
  return __builtin_bit_cast(__bf16, __float2bfloat16(f));
}

// async 16B/lane global->LDS DMA: dest = uniform base + lane*16, src per-lane
__device__ __forceinline__ void gl2lds16(const void* g, void* l) {
  __builtin_amdgcn_global_load_lds(
      (const __attribute__((address_space(1))) void*)g,
      (__attribute__((address_space(3))) void*)l, 16, 0, 0);
}

// histogram of row indices + W fp32 -> bf16 conversion
__global__ void prep_kernel(const int* __restrict__ rowidx, const float* __restrict__ W,
                            int* __restrict__ deg, __bf16* __restrict__ Wb, int n) {
  int i = blockIdx.x * blockDim.x + threadIdx.x;
  if (i < C * C) Wb[i] = f2b(W[i]);
  if (i < n) atomicAdd(deg + rowidx[i], 1);
}

// result[j] = (x[j] + x[col[j]]) @ W.T + 2*b + deg[j]
// ONE-SHOT blocks, hardware dispatch order (only floor-traffic regime).
// R10: R9 (DMA staging, best=182us) ran at 1 block/CU -> serial lifecycle
// (stage/sync/compute/store with ZERO bytes in flight after the barrier).
// Halve LDS to 64KB -> 2 blocks/CU: block k+1's DMA burst overlaps block k's
// barrier+compute+store. Dense rows move to direct global->reg (coalesced
// streaming loads; sink-tolerant); the latency-hostile GATHER stream stays
// register-free via DMA.
__launch_bounds__(256, 2)
__global__ void gconv_kernel(const float* __restrict__ x,
                             const int* __restrict__ colidx,
                             const __bf16* __restrict__ Wb,
                             const float* __restrict__ bias,
                             const int* __restrict__ deg,
                             float* __restrict__ out, int n) {
  __shared__ bf16x8 sW[2048];          // 32 KB: row r = slots [r*16,r*16+16), chunk c at slot c^(r&15)
  __shared__ float sG[BROWS * 128];    // 32 KB gather rows: chunk c of row r at slot c^(r&7)

  const int t = threadIdx.x;
  const int lane = t & 63, w = t >> 6;
  const int l15 = lane & 15, quad = lane >> 4;
  const int l31 = lane & 31, half = lane >> 5;
  const int base = blockIdx.x * BROWS;

  // ---- colidx for this wave's 16 rows (lane L holds row L&15) ----
  int gidx = base + w * 16 + l15;
  int cv = colidx[gidx < n ? gidx : n - 1];

  // ---- W via DMA: wave w stages W rows [w*32, w*32+32); 8 x 1KB ----
#pragma unroll
  for (int i = 0; i < 8; i++) {
    int r = w * 32 + i * 4 + (lane >> 4);
    const __bf16* src = Wb + r * C + (((lane & 15) ^ (r & 15)) << 3);
    gl2lds16(src, &sW[(w * 32 + i * 4) * 16]);
  }

  // ---- gather rows via DMA (per-lane random source addresses) ----
#pragma unroll
  for (int i = 0; i < 8; i++) {
    int rl = w * 16 + i * 2 + half;
    int cg = __shfl(cv, i * 2 + half);
    const float* src = x + (size_t)cg * C + ((l31 ^ (rl & 7)) << 2);
    gl2lds16(src, &sG[(w * 16 + i * 2) * 128]);
  }

  // ---- dense row: direct global->reg (coalesced; 8 x 16B per lane) ----
  int grow = base + w * 16 + l15; if (grow >= n) grow = n - 1;
  const floatx4* pa = (const floatx4*)(x + (size_t)grow * C) + quad * 2;
  floatx4 va[8];
#pragma unroll
  for (int kc = 0; kc < 4; kc++) {
    va[2 * kc]     = pa[kc * 8];
    va[2 * kc + 1] = pa[kc * 8 + 1];
  }

  // deg for the 4 epilogue rows of this lane (row = base + w*16 + quad*4 + r)
  int gr  = base + w * 16 + quad * 4;
  int grl = (gr + 3 < n) ? gr : ((n - 4) & ~3);
  int4 d4 = *(const int4*)(deg + grl);

  // per-lane bias (col = tt*16 + l15)
  float b2[8];
#pragma unroll
  for (int tt = 0; tt < 8; tt++) b2[tt] = 2.0f * bias[tt * 16 + l15];

  __syncthreads();   // drains DMA (vmcnt 0) + makes sW/sG visible

  // ---- build A fragments: dense regs + gather LDS ----
  const float* gR = sG + (w * 16 + l15) * 128;
  const int s7 = l15 & 7;

  bf16x8 av[4];
#pragma unroll
  for (int kc = 0; kc < 4; kc++) {
    int c0 = 2 * quad + 8 * kc;   // even chunk index
    floatx4 a0 = va[2 * kc], a1 = va[2 * kc + 1];
    floatx4 g0 = *(const floatx4*)(gR + (((c0)     ^ s7) << 2));
    floatx4 g1 = *(const floatx4*)(gR + (((c0 + 1) ^ s7) << 2));
    av[kc][0] = f2b(a0[0] + g0[0]); av[kc][1] = f2b(a0[1] + g0[1]);
    av[kc][2] = f2b(a0[2] + g0[2]); av[kc][3] = f2b(a0[3] + g0[3]);
    av[kc][4] = f2b(a1[0] + g1[0]); av[kc][5] = f2b(a1[1] + g1[1]);
    av[kc][6] = f2b(a1[2] + g1[2]); av[kc][7] = f2b(a1[3] + g1[3]);
  }

  // B frag (kc,tt): row nrow = tt*16+l15, chunk quad+kc*4 at slot (quad+kc*4)^l15
  const bf16x8* wr0 = sW + l15 * 16 + ((quad + 0)  ^ l15);
  const bf16x8* wr1 = sW + l15 * 16 + ((quad + 4)  ^ l15);
  const bf16x8* wr2 = sW + l15 * 16 + ((quad + 8)  ^ l15);
  const bf16x8* wr3 = sW + l15 * 16 + ((quad + 12) ^ l15);

  floatx4 acc[8];
#pragma unroll
  for (int i = 0; i < 8; i++) acc[i] = (floatx4){0.f, 0.f, 0.f, 0.f};

#pragma unroll
  for (int tt = 0; tt < 8; tt++) {
    acc[tt] = __builtin_amdgcn_mfma_f32_16x16x32_bf16(av[0], wr0[tt * 256], acc[tt], 0, 0, 0);
    acc[tt] = __builtin_amdgcn_mfma_f32_16x16x32_bf16(av[1], wr1[tt * 256], acc[tt], 0, 0, 0);
    acc[tt] = __builtin_amdgcn_mfma_f32_16x16x32_bf16(av[2], wr2[tt * 256], acc[tt], 0, 0, 0);
    acc[tt] = __builtin_amdgcn_mfma_f32_16x16x32_bf16(av[3], wr3[tt * 256], acc[tt], 0, 0, 0);
  }

  // ---- epilogue: C/D layout col=l15, row=quad*4+reg (HW-verified) ----
  float dvf[4];
  dvf[0] = (float)d4.x; dvf[1] = (float)d4.y;
  dvf[2] = (float)d4.z; dvf[3] = (float)d4.w;
#pragma unroll
  for (int r = 0; r < 4; r++) {
    int g = gr + r;
    if (g < n) {
      float* orow = out + (size_t)g * C + l15;
      float dv = dvf[r];
#pragma unroll
      for (int tt = 0; tt < 8; tt++) orow[tt * 16] = acc[tt][r] + b2[tt] + dv;
    }
  }
}

extern "C" void kernel_launch(void* const* d_in, const int* in_sizes, int n_in,
                              void* d_out, int out_size, void* d_ws, size_t ws_size,
                              hipStream_t stream) {
  const float* x    = (const float*)d_in[0];
  const int*   edge = (const int*)d_in[1];   // [2, n] flat: first n = row, next n = col
  const float* W    = (const float*)d_in[2];
  const float* bias = (const float*)d_in[3];
  float* out = (float*)d_out;

  const int n = in_sizes[0] / C;             // 500000

  int* deg = (int*)d_ws;
  size_t wb_off = ((size_t)n * sizeof(int) + 255) & ~(size_t)255;
  __bf16* Wb = (__bf16*)((char*)d_ws + wb_off);

  hipMemsetAsync(deg, 0, (size_t)n * sizeof(int), stream);

  int nb = (n + 255) / 256;
  prep_kernel<<<nb, 256, 0, stream>>>(edge, W, deg, Wb, n);

  int mb = (n + BROWS - 1) / BROWS;          // 7813 blocks, one 64-row tile each
  gconv_kernel<<<mb, 256, 0, stream>>>(x, edge + n, Wb, bias, deg, out, n);
}